// Round 8
// baseline (328.816 us; speedup 1.0000x reference)
//
#include <hip/hip_runtime.h>
#include <cstdint>
#include <cstddef>

#define WG 256
#define NPB 256          // nodes per bucket
#define NPB_SHIFT 8
#define CAP 9216         // slab capacity (mean 8192, sd ~90 -> +11 sigma)
#define BIN_CHUNK 4096   // edges per bin block (512 threads, 8/thread)
#define LIN_NPB 128      // lin: nodes per block (8 groups of 16, dbuf LDS)

typedef _Float16 half4 __attribute__((ext_vector_type(4)));

// staging entry: (src << 8) | (dst & 255)  -- src < 2^24

// ---------------------------------------------------------------------------
// lin body (R16 proven): 128 nodes per block, weights staged once, x dbuf.
// Layer 1 only (layer 2 is fused into k_gat<0>'s epilogue).
// ---------------------------------------------------------------------------
__device__ __forceinline__ void lin_block(const float* __restrict__ x,
                                          const float* __restrict__ Wl,
                                          const float* __restrict__ Wr,
                                          _Float16* __restrict__ xl,
                                          _Float16* __restrict__ xr,
                                          long base_n, int N, int Cin, int t,
                                          float* sl, float* sr,
                                          float* sx0, float* sx1) {
    for (int i = t; i < Cin * 32; i += 512) { sl[i] = Wl[i]; sr[i] = Wr[i]; }
    {   // prologue: stage group 0
        int cnt0 = (int)min((long)16, (long)N - base_n);
        if (cnt0 > 0)
            for (int i = t; i < cnt0 * Cin; i += 512)
                sx0[i] = x[base_n * Cin + i];
    }
    __syncthreads();
#pragma unroll 1
    for (int g = 0; g < LIN_NPB / 16; g++) {
        long n0 = base_n + (long)g * 16;
        if (n0 >= N) break;
        float* scur = (g & 1) ? sx1 : sx0;
        float* snxt = (g & 1) ? sx0 : sx1;
        long n1 = n0 + 16;
        if (g < LIN_NPB / 16 - 1 && n1 < N) {
            int cnt1 = (int)min((long)16, (long)N - n1);
            for (int i = t; i < cnt1 * Cin; i += 512)
                snxt[i] = x[n1 * Cin + i];
        }
        int cnt = (int)min((long)16, (long)N - n0);
        int n = t >> 5, h = t & 31;
        if (n < cnt) {
            float al = 0.f, ar = 0.f;
            for (int k = 0; k < Cin; k++) {
                float xv = scur[n * Cin + k];
                al = fmaf(xv, sl[k * 32 + h], al);
                ar = fmaf(xv, sr[k * 32 + h], ar);
            }
            xl[(n0 + n) * 32 + h] = (_Float16)al;
            xr[(n0 + n) * 32 + h] = (_Float16)ar;
        }
        __syncthreads();
    }
}

// ---------------------------------------------------------------------------
// Fused front kernel, four block ranges:
//   [0, binBlocks)                : LDS counting sort of edges into slabs
//   [binBlocks, +linBlocks)       : xl/xr = x @ Wl/Wr (layer 1, independent)
//   [binBlocks+linBlocks, +stB)   : gstart binary search (independent)
//   [+1]                          : W2 transpose to workspace (R19)
// ---------------------------------------------------------------------------
__global__ __launch_bounds__(512) void k_front(
        const int* __restrict__ esrc, const int* __restrict__ edst,
        int* __restrict__ gcnt, unsigned* __restrict__ staging,
        int E, int NB, int binBlocks,
        const float* __restrict__ x, const float* __restrict__ Wl,
        const float* __restrict__ Wr, _Float16* __restrict__ xl,
        _Float16* __restrict__ xr, int N, int Cin, int linBlocks,
        const int* __restrict__ batch, int* __restrict__ gstart, int G,
        int stBlocks, const float* __restrict__ W2l,
        const float* __restrict__ W2r, float* __restrict__ w2t) {
    __shared__ unsigned sval[BIN_CHUNK];        // 16KB (lin branch aliases it)
    __shared__ unsigned short sbkt[BIN_CHUNK];  // 8KB
    __shared__ int hist[512];
    __shared__ int cursor[512];
    __shared__ int gbase[512];
    __shared__ int wtot[8];
    __shared__ int stotal;

    int t = threadIdx.x;

    if (blockIdx.x < (unsigned)binBlocks) {
        // ---------------- bin: per-block counting sort by bucket ----------
        hist[t] = 0;
        __syncthreads();
        long base = (long)blockIdx.x * BIN_CHUNK;
        int vb[BIN_CHUNK / 512];
        unsigned vv[BIN_CHUNK / 512];
#pragma unroll
        for (int k = 0; k < BIN_CHUNK / 512; k++) {
            long e = base + k * 512 + t;
            int b = -1; unsigned v = 0;
            if (e < E) {
                int d = edst[e];
                b = d >> NPB_SHIFT;
                v = ((unsigned)esrc[e] << NPB_SHIFT) | (unsigned)(d & (NPB - 1));
                atomicAdd(&hist[b], 1);
            }
            vb[k] = b; vv[k] = v;
        }
        __syncthreads();
        // inclusive scan over 512 bins: wave shfl scan + wave-total combine
        int lane = t & 63, wvq = t >> 6;
        int c = hist[t];
        int v = c;
#pragma unroll
        for (int off = 1; off < 64; off <<= 1) {
            int u = __shfl_up(v, off);
            if (lane >= off) v += u;
        }
        if (lane == 63) wtot[wvq] = v;
        __syncthreads();
        int add = 0;
#pragma unroll
        for (int wq = 0; wq < 8; wq++) add += (wq < wvq) ? wtot[wq] : 0;
        int incl = v + add;
        int st = incl - c;                 // exclusive
        cursor[t] = st;
        if (t == 511) stotal = incl;
        int wb = 0;
        if (t < NB && c > 0) wb = atomicAdd(&gcnt[t], c);
        gbase[t] = wb + t * CAP - st;
        __syncthreads();
        // rank & scatter into LDS (sorted by bucket)
#pragma unroll
        for (int k = 0; k < BIN_CHUNK / 512; k++) {
            int b = vb[k];
            if (b >= 0) {
                int r = atomicAdd(&cursor[b], 1);
                sval[r] = vv[k];
                sbkt[r] = (unsigned short)b;
            }
        }
        __syncthreads();
        // coalesced write-out (consecutive j -> consecutive addr per run)
        int total = stotal;
        for (int j = t; j < total; j += 512) {
            int b = sbkt[j];
            int addr = gbase[b] + j;
            if (addr < (b + 1) * CAP)      // statistical-impossibility guard
                staging[addr] = sval[j];
        }
    } else if (blockIdx.x < (unsigned)(binBlocks + linBlocks)) {
        // ---------------- lin: 128 nodes, weights staged once, x dbuf ----
        float* sl  = (float*)sval;                  // Cin*32 floats (<=1024)
        float* sr  = (float*)sval + 1024;           // Cin*32 floats
        float* sx0 = (float*)sval + 2048;           // 16*Cin floats
        float* sx1 = sx0 + 16 * Cin;                // 16*Cin floats
        long base_n = (long)(blockIdx.x - binBlocks) * LIN_NPB;
        lin_block(x, Wl, Wr, xl, xr, base_n, N, Cin, t, sl, sr, sx0, sx1);
    } else if (blockIdx.x < (unsigned)(binBlocks + linBlocks + stBlocks)) {
        // ---------------- starts: gstart via binary search ---------------
        int g = (blockIdx.x - binBlocks - linBlocks) * 512 + t;
        if (g <= G) {
            int lo = 0, hi = N;
            while (lo < hi) {
                int mid = (lo + hi) >> 1;
                if (batch[mid] < g) lo = mid + 1; else hi = mid;
            }
            gstart[g] = lo;
        }
    } else {
        // ---------------- trans: W2l^T / W2r^T to workspace (R19) --------
        for (int i = t; i < 1024; i += 512) {
            int k = i >> 5, c = i & 31;
            w2t[c * 32 + k]        = W2l[i];   // W2lt[c][k]
            w2t[1024 + c * 32 + k] = W2r[i];   // W2rt[c][k]
        }
    }
}

// ---------------------------------------------------------------------------
// Per-bucket (512 threads): prefix over gcnt via wave reduce; slab staged to
// LDS with fused histogram; 256-scan via wave shfl scan; offsets + self loop;
// place from LDS. Int LDS atomics only.
// ---------------------------------------------------------------------------
__global__ __launch_bounds__(512) void k_bucket(const unsigned* __restrict__ staging,
                                                const int* __restrict__ gcnt,
                                                int* __restrict__ offsets,
                                                int* __restrict__ csr_src,
                                                int N, int NB) {
    __shared__ unsigned sslab[CAP];            // 36KB
    __shared__ int hist[NPB];
    __shared__ int cur[NPB];
    __shared__ int wtot[8];
    int b = blockIdx.x;
    int t = threadIdx.x;
    int lane = t & 63, wv = t >> 6;

    // prefix over buckets < b (edges + self loops): partials + wave reduce
    int a = 0;
    for (int j = t; j < b; j += 512)
        a += min(gcnt[j], CAP) + min(NPB, N - j * NPB);
#pragma unroll
    for (int off = 1; off < 64; off <<= 1) a += __shfl_xor(a, off);
    if (lane == 0) wtot[wv] = a;
    if (t < NPB) hist[t] = 0;
    __syncthreads();
    int bbase = wtot[0] + wtot[1] + wtot[2] + wtot[3]
              + wtot[4] + wtot[5] + wtot[6] + wtot[7];

    int cnt = min(gcnt[b], CAP);
    const unsigned* slab = staging + (long)b * CAP;
    for (int j = t; j < cnt; j += 512) {
        unsigned e = slab[j];
        sslab[j] = e;
        atomicAdd(&hist[e & (NPB - 1)], 1);
    }
    if (b == NB - 1 && t == 0)
        offsets[N] = bbase + cnt + min(NPB, N - b * NPB);
    __syncthreads();

    // scan over 256 node-counts: waves 0..3, shfl inclusive scan
    int node = b * NPB + t;
    int c = 0, v = 0;
    if (t < NPB) {
        c = (node < N) ? hist[t] + 1 : 0;      // +1 self loop
        v = c;
#pragma unroll
        for (int off = 1; off < 64; off <<= 1) {
            int u = __shfl_up(v, off);
            if (lane >= off) v += u;
        }
        if (lane == 63) wtot[wv] = v;          // wv 0..3 (safe: bbase already read)
    }
    __syncthreads();
    if (t < NPB) {
        int add = (wv >= 1 ? wtot[0] : 0) + (wv >= 2 ? wtot[1] : 0)
                + (wv >= 3 ? wtot[2] : 0);
        int o = bbase + (v + add) - c;         // exclusive
        if (node < N) {
            offsets[node] = o;
            csr_src[o] = node;                 // self loop first
            cur[t] = o + 1;
        }
    }
    __syncthreads();
    for (int j = t; j < cnt; j += 512) {
        unsigned e = sslab[j];
        int p = atomicAdd(&cur[e & (NPB - 1)], 1);
        csr_src[p] = (int)(e >> NPB_SHIFT);
    }
}

// ---------------------------------------------------------------------------
// Fused GATv2 aggregation. Main loop = EXACT R14 version (3x-measured floor:
// 52.6-53.4us, FETCH ~104MB = L2-capacity miss rate on the 64B-row gather).
// MODE 0 (layer 1): epilogue computes xl2/xr2 = relu(h)@Wl2/Wr2.
//   R18: h-rows via wave-local LDS round-trip (87.7 -> 74.3us vs bpermute).
//   R19: weights read from PRE-TRANSPOSED W2 (k_front writes W2^T to ws) --
//   the 64 stride-32 scalar VMEM loads (measured ~1000cyc/wave, latency
//   exposed at wave end) become 16 coalesced dwordx4 from an L1-resident
//   8KB table. FMA order k-ascending unchanged -> bitwise identical.
// MODE 1 (layer 2): proven coalesced fp32 row write.
// Lane layout: e8 = lane>>3 (edge within 8-batch), hq = lane&7 (h-quad).
// ---------------------------------------------------------------------------
template <int MODE>
__global__ __launch_bounds__(WG) void k_gat(
        const _Float16* __restrict__ xl, const _Float16* __restrict__ xr,
        const int* __restrict__ offsets, const int* __restrict__ csr,
        const float* __restrict__ att, const float* __restrict__ bias,
        int N,
        const float* __restrict__ w2t,
        _Float16* __restrict__ oxl, _Float16* __restrict__ oxr,
        float* __restrict__ out) {
    __shared__ float sO[WG / 64][2][32];       // 1KB: per-wave h-rows (MODE 0)
    int lane = threadIdx.x & 63;
    int wv = threadIdx.x >> 6;
    int wid = blockIdx.x * (WG / 64) + wv;
    int iA = wid * 2;
    if (iA >= N) return;
    int iB = iA + 1;
    int e8 = lane >> 3;
    int hq = lane & 7;
    unsigned hq8 = (unsigned)hq << 3;          // byte offset of h-quad in 64B row

    const char* xlb = (const char*)xl;
    const char* csrb = (const char*)csr;

    int startA = offsets[iA], endA = offsets[iA + 1];
    int startB = 0, endB = 0;
    if (iB < N) { startB = endA; endB = offsets[iB + 1]; }

    float4 att4 = *(const float4*)(att + hq * 4);
    const float L2E = 1.4426950408889634f;
    att4.x *= L2E; att4.y *= L2E; att4.z *= L2E; att4.w *= L2E;

    const _Float16 ns = (_Float16)0.2f;
    half4 hzero = {(_Float16)0.f, (_Float16)0.f, (_Float16)0.f, (_Float16)0.f};

    half4 xrA = *(const half4*)(xr + (long)iA * 32 + hq * 4);
    half4 xrB = hzero;
    if (iB < N) xrB = *(const half4*)(xr + (long)iB * 32 + hq * 4);

    float denomA = 0.f, denomB = 0.f;
    float4 accA = {0.f, 0.f, 0.f, 0.f};
    float4 accB = {0.f, 0.f, 0.f, 0.f};

    int itA = (endA - startA + 7) >> 3;
    int itB = (endB - startB + 7) >> 3;
    int iters = max(itA, itB);

    int pA = startA + e8, pB = startB + e8;
    int sA = -1, sB = -1;
    if (pA < endA) sA = *(const int*)(csrb + ((unsigned)pA << 2));
    if (pB < endB) sB = *(const int*)(csrb + ((unsigned)pB << 2));

    for (int it = 0; it < iters; ++it) {
        half4 xa = hzero;
        half4 xb = hzero;
        if (sA >= 0) xa = *(const half4*)(xlb + (((unsigned)sA << 6) | hq8));
        if (sB >= 0) xb = *(const half4*)(xlb + (((unsigned)sB << 6) | hq8));
        // prefetch next iteration's csr indices (independent of compute)
        pA += 8; pB += 8;
        int sA2 = -1, sB2 = -1;
        if (pA < endA) sA2 = *(const int*)(csrb + ((unsigned)pA << 2));
        if (pB < endB) sB2 = *(const int*)(csrb + ((unsigned)pB << 2));

        // ---- stream A ----
        {
            half4 s = xa + xrA;                          // 2x v_pk_add_f16
            half4 m = s * ns;                            // 2x v_pk_mul_f16
            half4 tt = __builtin_elementwise_max(s, m);  // 2x v_pk_max_f16
            float l = fmaf((float)tt[0], att4.x,
                      fmaf((float)tt[1], att4.y,
                      fmaf((float)tt[2], att4.z,
                           (float)tt[3] * att4.w)));     // v_fma_mix chain
            l += __shfl_xor(l, 1);
            l += __shfl_xor(l, 2);
            l += __shfl_xor(l, 4);
            float wA = __builtin_amdgcn_exp2f(l);        // l is log2-scaled
            wA = (sA >= 0) ? wA : 0.f;
            denomA += wA;
            accA.x = fmaf(wA, (float)xa[0], accA.x);     // v_fma_mix
            accA.y = fmaf(wA, (float)xa[1], accA.y);
            accA.z = fmaf(wA, (float)xa[2], accA.z);
            accA.w = fmaf(wA, (float)xa[3], accA.w);
        }
        // ---- stream B ----
        {
            half4 s = xb + xrB;
            half4 m = s * ns;
            half4 tt = __builtin_elementwise_max(s, m);
            float l = fmaf((float)tt[0], att4.x,
                      fmaf((float)tt[1], att4.y,
                      fmaf((float)tt[2], att4.z,
                           (float)tt[3] * att4.w)));
            l += __shfl_xor(l, 1);
            l += __shfl_xor(l, 2);
            l += __shfl_xor(l, 4);
            float wB = __builtin_amdgcn_exp2f(l);
            wB = (sB >= 0) ? wB : 0.f;
            denomB += wB;
            accB.x = fmaf(wB, (float)xb[0], accB.x);
            accB.y = fmaf(wB, (float)xb[1], accB.y);
            accB.z = fmaf(wB, (float)xb[2], accB.z);
            accB.w = fmaf(wB, (float)xb[3], accB.w);
        }
        sA = sA2; sB = sB2;
    }

    // reduce across the 8 edge groups (xor 8,16,32) -> ALL lanes hold sums
    denomA += __shfl_xor(denomA, 8); denomA += __shfl_xor(denomA, 16); denomA += __shfl_xor(denomA, 32);
    denomB += __shfl_xor(denomB, 8); denomB += __shfl_xor(denomB, 16); denomB += __shfl_xor(denomB, 32);
    accA.x += __shfl_xor(accA.x, 8); accA.x += __shfl_xor(accA.x, 16); accA.x += __shfl_xor(accA.x, 32);
    accA.y += __shfl_xor(accA.y, 8); accA.y += __shfl_xor(accA.y, 16); accA.y += __shfl_xor(accA.y, 32);
    accA.z += __shfl_xor(accA.z, 8); accA.z += __shfl_xor(accA.z, 16); accA.z += __shfl_xor(accA.z, 32);
    accA.w += __shfl_xor(accA.w, 8); accA.w += __shfl_xor(accA.w, 16); accA.w += __shfl_xor(accA.w, 32);
    accB.x += __shfl_xor(accB.x, 8); accB.x += __shfl_xor(accB.x, 16); accB.x += __shfl_xor(accB.x, 32);
    accB.y += __shfl_xor(accB.y, 8); accB.y += __shfl_xor(accB.y, 16); accB.y += __shfl_xor(accB.y, 32);
    accB.z += __shfl_xor(accB.z, 8); accB.z += __shfl_xor(accB.z, 16); accB.z += __shfl_xor(accB.z, 32);
    accB.w += __shfl_xor(accB.w, 8); accB.w += __shfl_xor(accB.w, 16); accB.w += __shfl_xor(accB.w, 32);

    const float4 b4 = *(const float4*)(bias + hq * 4);

    if (MODE == 0) {
        // build outputs (all lanes -- cheap, SIMD)
        float invA = 1.0f / denomA;
        float4 oA;
        oA.x = fmaxf(fmaf(accA.x, invA, b4.x), 0.f);
        oA.y = fmaxf(fmaf(accA.y, invA, b4.y), 0.f);
        oA.z = fmaxf(fmaf(accA.z, invA, b4.z), 0.f);
        oA.w = fmaxf(fmaf(accA.w, invA, b4.w), 0.f);
        float4 oB = {0.f, 0.f, 0.f, 0.f};
        if (iB < N) {
            float invB = 1.0f / denomB;
            oB.x = fmaxf(fmaf(accB.x, invB, b4.x), 0.f);
            oB.y = fmaxf(fmaf(accB.y, invB, b4.y), 0.f);
            oB.z = fmaxf(fmaf(accB.z, invB, b4.z), 0.f);
            oB.w = fmaxf(fmaf(accB.w, invB, b4.w), 0.f);
        }
        // stage the two h-rows in wave-local LDS (broadcast source)
        if (lane < 8) {
            *(float4*)&sO[wv][0][hq * 4] = oA;
        } else if (lane < 16) {
            *(float4*)&sO[wv][1][hq * 4] = oB;   // garbage ok if iB>=N (unused)
        }
        __builtin_amdgcn_wave_barrier();         // pin write->read order
        // layer-2 matvec: lane l -> output col (l&31) of node (l>>5).
        // Weights from pre-transposed table: contiguous dwordx4 reads.
        int hcol = lane & 31;
        int nrow = lane >> 5;
        const float* row = &sO[wv][nrow][0];
        const float* wlt = w2t + hcol * 32;          // W2lt row
        const float* wrt = w2t + 1024 + hcol * 32;   // W2rt row
        float al = 0.f, ar = 0.f;
#pragma unroll
        for (int kb = 0; kb < 8; kb++) {
            float4 r4 = *(const float4*)(row + kb * 4);    // ds_read_b128 bcast
            float4 wl4 = *(const float4*)(wlt + kb * 4);   // global dwordx4
            float4 wr4 = *(const float4*)(wrt + kb * 4);
            al = fmaf(r4.x, wl4.x, al);
            ar = fmaf(r4.x, wr4.x, ar);
            al = fmaf(r4.y, wl4.y, al);
            ar = fmaf(r4.y, wr4.y, ar);
            al = fmaf(r4.z, wl4.z, al);
            ar = fmaf(r4.z, wr4.z, ar);
            al = fmaf(r4.w, wl4.w, al);
            ar = fmaf(r4.w, wr4.w, ar);
        }
        long nn = nrow ? (long)iB : (long)iA;
        if (!nrow || iB < N) {
            oxl[nn * 32 + hcol] = (_Float16)al;
            oxr[nn * 32 + hcol] = (_Float16)ar;
        }
    } else {
        // proven coalesced fp32 row write (R0-R4 epilogue)
        if (lane < 8) {
            float inv = 1.0f / denomA;
            float4 o;
            o.x = fmaxf(fmaf(accA.x, inv, b4.x), 0.f);
            o.y = fmaxf(fmaf(accA.y, inv, b4.y), 0.f);
            o.z = fmaxf(fmaf(accA.z, inv, b4.z), 0.f);
            o.w = fmaxf(fmaf(accA.w, inv, b4.w), 0.f);
            *(float4*)(out + (long)iA * 32 + hq * 4) = o;
        } else if (lane < 16 && iB < N) {
            float inv = 1.0f / denomB;
            float4 o;
            o.x = fmaxf(fmaf(accB.x, inv, b4.x), 0.f);
            o.y = fmaxf(fmaf(accB.y, inv, b4.y), 0.f);
            o.z = fmaxf(fmaf(accB.z, inv, b4.z), 0.f);
            o.w = fmaxf(fmaf(accB.w, inv, b4.w), 0.f);
            *(float4*)(out + (long)iB * 32 + hq * 4) = o;
        }
    }
}

// ---------------------------------------------------------------------------
// Fused mean-pool + linear head (R0-R4 proven): one block per graph,
// sequential coalesced h2v reads, zero atomics.
// ---------------------------------------------------------------------------
__global__ __launch_bounds__(WG) void k_pool(const float* __restrict__ h2v,
                                             const int* __restrict__ gstart,
                                             const float* __restrict__ Wlin,
                                             const float* __restrict__ blin,
                                             float* __restrict__ out, int G) {
    __shared__ float red[WG];
    int g = blockIdx.x;
    int t = threadIdx.x;
    int h = t & 31;
    int grp = t >> 5;                       // 8 groups of 32 lanes
    int s = gstart[g], e = gstart[g + 1];
    float acc = 0.f;
    for (int n = s + grp; n < e; n += 8)
        acc += h2v[(long)n * 32 + h];
    red[t] = acc;
    __syncthreads();
    if (grp == 0) {
        float a = red[h] + red[h + 32] + red[h + 64] + red[h + 96]
                + red[h + 128] + red[h + 160] + red[h + 192] + red[h + 224];
        int cnt = e - s;
        float c = (float)(cnt > 1 ? cnt : 1);
        float f = a / c;
        out[G * 4 + g * 32 + h] = f;        // features block
        float p0 = f * Wlin[h * 4 + 0];
        float p1 = f * Wlin[h * 4 + 1];
        float p2 = f * Wlin[h * 4 + 2];
        float p3 = f * Wlin[h * 4 + 3];
        for (int off = 1; off < 32; off <<= 1) {
            p0 += __shfl_xor(p0, off);
            p1 += __shfl_xor(p1, off);
            p2 += __shfl_xor(p2, off);
            p3 += __shfl_xor(p3, off);
        }
        if (h == 0) {
            out[g * 4 + 0] = p0 + blin[0];
            out[g * 4 + 1] = p1 + blin[1];
            out[g * 4 + 2] = p2 + blin[2];
            out[g * 4 + 3] = p3 + blin[3];
        }
    }
}

// ---------------------------------------------------------------------------
extern "C" void kernel_launch(void* const* d_in, const int* in_sizes, int n_in,
                              void* d_out, int out_size, void* d_ws, size_t ws_size,
                              hipStream_t stream) {
    const float* x    = (const float*)d_in[0];
    const int*   ei   = (const int*)d_in[1];
    const int*   batch= (const int*)d_in[2];
    const float* Wl1  = (const float*)d_in[3];
    const float* Wr1  = (const float*)d_in[4];
    const float* att1 = (const float*)d_in[5];
    const float* b1   = (const float*)d_in[6];
    const float* Wl2  = (const float*)d_in[7];
    const float* Wr2  = (const float*)d_in[8];
    const float* att2 = (const float*)d_in[9];
    const float* b2   = (const float*)d_in[10];
    const float* Wlin = (const float*)d_in[11];
    const float* blin = (const float*)d_in[12];
    float* out = (float*)d_out;

    const int N   = in_sizes[2];
    const int Cin = in_sizes[0] / N;
    const int E   = in_sizes[1] / 2;
    const int G   = out_size / 36;
    const int* src = ei;
    const int* dst = ei + E;
    const int NB  = (N + NPB - 1) >> NPB_SHIFT;   // buckets (<=512)

    // workspace carve (256B aligned)
    char* w = (char*)d_ws;
    auto alloc = [&](size_t bytes) {
        char* p = w;
        w += (bytes + 255) & ~(size_t)255;
        return p;
    };
    int* offsets = (int*)alloc((size_t)(N + 1) * 4);
    int* gstart  = (int*)alloc((size_t)(G + 1) * 4);
    int* gcnt    = (int*)alloc((size_t)NB * 4);
    int* csr_src = (int*)alloc((size_t)(E + N) * 4);
    unsigned* staging = (unsigned*)alloc((size_t)NB * CAP * 4);
    float* w2t   = (float*)alloc((size_t)2048 * 4);
    _Float16* xl  = (_Float16*)alloc((size_t)N * 32 * 2);
    _Float16* xr  = (_Float16*)alloc((size_t)N * 32 * 2);
    _Float16* xl2 = (_Float16*)alloc((size_t)N * 32 * 2);
    _Float16* xr2 = (_Float16*)alloc((size_t)N * 32 * 2);
    float* h2v    = (float*)alloc((size_t)N * 32 * 4);

    hipMemsetAsync(gcnt, 0, (size_t)NB * 4, stream);

    int binBlocks = (E + BIN_CHUNK - 1) / BIN_CHUNK;
    int linBlocks = (N + LIN_NPB - 1) / LIN_NPB;
    int stBlocks  = (G + 1 + 511) / 512;

    // front: CSR bin + layer-1 lin + gstart + W2 transpose, one kernel
    k_front<<<binBlocks + linBlocks + stBlocks + 1, 512, 0, stream>>>(
        src, dst, gcnt, staging, E, NB, binBlocks,
        x, Wl1, Wr1, xl, xr, N, Cin, linBlocks,
        batch, gstart, G, stBlocks, Wl2, Wr2, w2t);

    // CSR place (512 threads, LDS-staged slab, wave-scan)
    k_bucket<<<NB, 512, 0, stream>>>(staging, gcnt, offsets, csr_src, N, NB);

    int waves = (N + 1) / 2;
    int gat_grid = (waves + 3) / 4;               // 4 waves per 256-block

    // layer 1 aggregate + fused layer-2 transform (writes xl2/xr2 directly)
    k_gat<0><<<gat_grid, WG, 0, stream>>>(xl, xr, offsets, csr_src, att1, b1,
                                          N, w2t, xl2, xr2, nullptr);

    // layer 2 aggregate, fp32 rows to h2v
    k_gat<1><<<gat_grid, WG, 0, stream>>>(xl2, xr2, offsets, csr_src, att2, b2,
                                          N, nullptr, nullptr, nullptr, h2v);

    // pool + head
    k_pool<<<G, WG, 0, stream>>>(h2v, gstart, Wlin, blin, out, G);
}

// Round 9
// 267.954 us; speedup vs baseline: 1.2271x; 1.2271x over previous
//
#include <hip/hip_runtime.h>
#include <cstdint>
#include <cstddef>

#define WG 256
#define NPB 256          // nodes per bucket
#define NPB_SHIFT 8
#define CAP 9216         // slab capacity (mean 8192, sd ~90 -> +11 sigma)
#define BIN_CHUNK 4096   // edges per bin block (512 threads, 8/thread)
#define LIN_NPB 128      // lin: nodes per block (8 groups of 16, dbuf LDS)

typedef _Float16 half4 __attribute__((ext_vector_type(4)));

// staging entry: (src << 8) | (dst & 255)  -- src < 2^24

// ---------------------------------------------------------------------------
// lin body (R16 proven): 128 nodes per block, weights staged once, x dbuf.
// Layer 1 only (layer 2 is fused into k_gat<0>'s epilogue).
// ---------------------------------------------------------------------------
__device__ __forceinline__ void lin_block(const float* __restrict__ x,
                                          const float* __restrict__ Wl,
                                          const float* __restrict__ Wr,
                                          _Float16* __restrict__ xl,
                                          _Float16* __restrict__ xr,
                                          long base_n, int N, int Cin, int t,
                                          float* sl, float* sr,
                                          float* sx0, float* sx1) {
    for (int i = t; i < Cin * 32; i += 512) { sl[i] = Wl[i]; sr[i] = Wr[i]; }
    {   // prologue: stage group 0
        int cnt0 = (int)min((long)16, (long)N - base_n);
        if (cnt0 > 0)
            for (int i = t; i < cnt0 * Cin; i += 512)
                sx0[i] = x[base_n * Cin + i];
    }
    __syncthreads();
#pragma unroll 1
    for (int g = 0; g < LIN_NPB / 16; g++) {
        long n0 = base_n + (long)g * 16;
        if (n0 >= N) break;
        float* scur = (g & 1) ? sx1 : sx0;
        float* snxt = (g & 1) ? sx0 : sx1;
        long n1 = n0 + 16;
        if (g < LIN_NPB / 16 - 1 && n1 < N) {
            int cnt1 = (int)min((long)16, (long)N - n1);
            for (int i = t; i < cnt1 * Cin; i += 512)
                snxt[i] = x[n1 * Cin + i];
        }
        int cnt = (int)min((long)16, (long)N - n0);
        int n = t >> 5, h = t & 31;
        if (n < cnt) {
            float al = 0.f, ar = 0.f;
            for (int k = 0; k < Cin; k++) {
                float xv = scur[n * Cin + k];
                al = fmaf(xv, sl[k * 32 + h], al);
                ar = fmaf(xv, sr[k * 32 + h], ar);
            }
            xl[(n0 + n) * 32 + h] = (_Float16)al;
            xr[(n0 + n) * 32 + h] = (_Float16)ar;
        }
        __syncthreads();
    }
}

// ---------------------------------------------------------------------------
// Fused front kernel, four block ranges:
//   [0, binBlocks)                : LDS counting sort of edges into slabs
//   [binBlocks, +linBlocks)       : xl/xr = x @ Wl/Wr (layer 1, independent)
//   [binBlocks+linBlocks, +stB)   : gstart binary search (independent)
//   [+1]                          : W2 quad-k repack to workspace (R20)
// ---------------------------------------------------------------------------
__global__ __launch_bounds__(512) void k_front(
        const int* __restrict__ esrc, const int* __restrict__ edst,
        int* __restrict__ gcnt, unsigned* __restrict__ staging,
        int E, int NB, int binBlocks,
        const float* __restrict__ x, const float* __restrict__ Wl,
        const float* __restrict__ Wr, _Float16* __restrict__ xl,
        _Float16* __restrict__ xr, int N, int Cin, int linBlocks,
        const int* __restrict__ batch, int* __restrict__ gstart, int G,
        int stBlocks, const float* __restrict__ W2l,
        const float* __restrict__ W2r, float* __restrict__ w2t) {
    __shared__ unsigned sval[BIN_CHUNK];        // 16KB (lin branch aliases it)
    __shared__ unsigned short sbkt[BIN_CHUNK];  // 8KB
    __shared__ int hist[512];
    __shared__ int cursor[512];
    __shared__ int gbase[512];
    __shared__ int wtot[8];
    __shared__ int stotal;

    int t = threadIdx.x;

    if (blockIdx.x < (unsigned)binBlocks) {
        // ---------------- bin: per-block counting sort by bucket ----------
        hist[t] = 0;
        __syncthreads();
        long base = (long)blockIdx.x * BIN_CHUNK;
        int vb[BIN_CHUNK / 512];
        unsigned vv[BIN_CHUNK / 512];
#pragma unroll
        for (int k = 0; k < BIN_CHUNK / 512; k++) {
            long e = base + k * 512 + t;
            int b = -1; unsigned v = 0;
            if (e < E) {
                int d = edst[e];
                b = d >> NPB_SHIFT;
                v = ((unsigned)esrc[e] << NPB_SHIFT) | (unsigned)(d & (NPB - 1));
                atomicAdd(&hist[b], 1);
            }
            vb[k] = b; vv[k] = v;
        }
        __syncthreads();
        // inclusive scan over 512 bins: wave shfl scan + wave-total combine
        int lane = t & 63, wvq = t >> 6;
        int c = hist[t];
        int v = c;
#pragma unroll
        for (int off = 1; off < 64; off <<= 1) {
            int u = __shfl_up(v, off);
            if (lane >= off) v += u;
        }
        if (lane == 63) wtot[wvq] = v;
        __syncthreads();
        int add = 0;
#pragma unroll
        for (int wq = 0; wq < 8; wq++) add += (wq < wvq) ? wtot[wq] : 0;
        int incl = v + add;
        int st = incl - c;                 // exclusive
        cursor[t] = st;
        if (t == 511) stotal = incl;
        int wb = 0;
        if (t < NB && c > 0) wb = atomicAdd(&gcnt[t], c);
        gbase[t] = wb + t * CAP - st;
        __syncthreads();
        // rank & scatter into LDS (sorted by bucket)
#pragma unroll
        for (int k = 0; k < BIN_CHUNK / 512; k++) {
            int b = vb[k];
            if (b >= 0) {
                int r = atomicAdd(&cursor[b], 1);
                sval[r] = vv[k];
                sbkt[r] = (unsigned short)b;
            }
        }
        __syncthreads();
        // coalesced write-out (consecutive j -> consecutive addr per run)
        int total = stotal;
        for (int j = t; j < total; j += 512) {
            int b = sbkt[j];
            int addr = gbase[b] + j;
            if (addr < (b + 1) * CAP)      // statistical-impossibility guard
                staging[addr] = sval[j];
        }
    } else if (blockIdx.x < (unsigned)(binBlocks + linBlocks)) {
        // ---------------- lin: 128 nodes, weights staged once, x dbuf ----
        float* sl  = (float*)sval;                  // Cin*32 floats (<=1024)
        float* sr  = (float*)sval + 1024;           // Cin*32 floats
        float* sx0 = (float*)sval + 2048;           // 16*Cin floats
        float* sx1 = sx0 + 16 * Cin;                // 16*Cin floats
        long base_n = (long)(blockIdx.x - binBlocks) * LIN_NPB;
        lin_block(x, Wl, Wr, xl, xr, base_n, N, Cin, t, sl, sr, sx0, sx1);
    } else if (blockIdx.x < (unsigned)(binBlocks + linBlocks + stBlocks)) {
        // ---------------- starts: gstart via binary search ---------------
        int g = (blockIdx.x - binBlocks - linBlocks) * 512 + t;
        if (g <= G) {
            int lo = 0, hi = N;
            while (lo < hi) {
                int mid = (lo + hi) >> 1;
                if (batch[mid] < g) lo = mid + 1; else hi = mid;
            }
            gstart[g] = lo;
        }
    } else {
        // ---------------- repack: W2 quad-k layout (R20) -----------------
        // w2q float4[kb*32 + c] = {W2[4kb][c], W2[4kb+1][c], W2[4kb+2][c],
        //  W2[4kb+3][c]} -- lane hcol loads float4 at 16B stride (dense 1KB
        //  wave footprint, fully-utilized lines). R19's row-major transpose
        //  (128B lane stride, 1/8 line utilization) cost +53us; coalescing
        //  is a wave-footprint property, not a per-lane one.
        for (int i = t; i < 1024; i += 512) {
            int k = i >> 5, c = i & 31;
            int q = (k >> 2) * 128 + c * 4 + (k & 3);
            w2t[q]        = W2l[i];
            w2t[1024 + q] = W2r[i];
        }
    }
}

// ---------------------------------------------------------------------------
// Per-bucket (512 threads): prefix over gcnt via wave reduce; slab staged to
// LDS with fused histogram; 256-scan via wave shfl scan; offsets + self loop;
// place from LDS. Int LDS atomics only.
// ---------------------------------------------------------------------------
__global__ __launch_bounds__(512) void k_bucket(const unsigned* __restrict__ staging,
                                                const int* __restrict__ gcnt,
                                                int* __restrict__ offsets,
                                                int* __restrict__ csr_src,
                                                int N, int NB) {
    __shared__ unsigned sslab[CAP];            // 36KB
    __shared__ int hist[NPB];
    __shared__ int cur[NPB];
    __shared__ int wtot[8];
    int b = blockIdx.x;
    int t = threadIdx.x;
    int lane = t & 63, wv = t >> 6;

    // prefix over buckets < b (edges + self loops): partials + wave reduce
    int a = 0;
    for (int j = t; j < b; j += 512)
        a += min(gcnt[j], CAP) + min(NPB, N - j * NPB);
#pragma unroll
    for (int off = 1; off < 64; off <<= 1) a += __shfl_xor(a, off);
    if (lane == 0) wtot[wv] = a;
    if (t < NPB) hist[t] = 0;
    __syncthreads();
    int bbase = wtot[0] + wtot[1] + wtot[2] + wtot[3]
              + wtot[4] + wtot[5] + wtot[6] + wtot[7];

    int cnt = min(gcnt[b], CAP);
    const unsigned* slab = staging + (long)b * CAP;
    for (int j = t; j < cnt; j += 512) {
        unsigned e = slab[j];
        sslab[j] = e;
        atomicAdd(&hist[e & (NPB - 1)], 1);
    }
    if (b == NB - 1 && t == 0)
        offsets[N] = bbase + cnt + min(NPB, N - b * NPB);
    __syncthreads();

    // scan over 256 node-counts: waves 0..3, shfl inclusive scan
    int node = b * NPB + t;
    int c = 0, v = 0;
    if (t < NPB) {
        c = (node < N) ? hist[t] + 1 : 0;      // +1 self loop
        v = c;
#pragma unroll
        for (int off = 1; off < 64; off <<= 1) {
            int u = __shfl_up(v, off);
            if (lane >= off) v += u;
        }
        if (lane == 63) wtot[wv] = v;          // wv 0..3 (safe: bbase already read)
    }
    __syncthreads();
    if (t < NPB) {
        int add = (wv >= 1 ? wtot[0] : 0) + (wv >= 2 ? wtot[1] : 0)
                + (wv >= 3 ? wtot[2] : 0);
        int o = bbase + (v + add) - c;         // exclusive
        if (node < N) {
            offsets[node] = o;
            csr_src[o] = node;                 // self loop first
            cur[t] = o + 1;
        }
    }
    __syncthreads();
    for (int j = t; j < cnt; j += 512) {
        unsigned e = sslab[j];
        int p = atomicAdd(&cur[e & (NPB - 1)], 1);
        csr_src[p] = (int)(e >> NPB_SHIFT);
    }
}

// ---------------------------------------------------------------------------
// Fused GATv2 aggregation. Main loop = EXACT R14 version (3x-measured floor:
// 52.6-53.4us, FETCH ~104MB = L2-capacity miss rate on the 64B-row gather).
// MODE 0 (layer 1): epilogue computes xl2/xr2 = relu(h)@Wl2/Wr2.
//   R18: h-rows via wave-local LDS round-trip (87.7 -> 74.3 vs bpermute).
//   R20: weights from quad-k-packed w2q: 16 coalesced dwordx4 (dense wave
//   footprint) replace R18's 64 coalesced scalar loads. FMA order k-asc
//   unchanged -> bitwise identical to R18. (R19's row-transpose was
//   UNcoalesced -- 32 lines/inst at 1/8 utilization, +53us -- reverted.)
// MODE 1 (layer 2): proven coalesced fp32 row write.
// Lane layout: e8 = lane>>3 (edge within 8-batch), hq = lane&7 (h-quad).
// ---------------------------------------------------------------------------
template <int MODE>
__global__ __launch_bounds__(WG) void k_gat(
        const _Float16* __restrict__ xl, const _Float16* __restrict__ xr,
        const int* __restrict__ offsets, const int* __restrict__ csr,
        const float* __restrict__ att, const float* __restrict__ bias,
        int N,
        const float* __restrict__ w2t,
        _Float16* __restrict__ oxl, _Float16* __restrict__ oxr,
        float* __restrict__ out) {
    __shared__ float sO[WG / 64][2][32];       // 1KB: per-wave h-rows (MODE 0)
    int lane = threadIdx.x & 63;
    int wv = threadIdx.x >> 6;
    int wid = blockIdx.x * (WG / 64) + wv;
    int iA = wid * 2;
    if (iA >= N) return;
    int iB = iA + 1;
    int e8 = lane >> 3;
    int hq = lane & 7;
    unsigned hq8 = (unsigned)hq << 3;          // byte offset of h-quad in 64B row

    const char* xlb = (const char*)xl;
    const char* csrb = (const char*)csr;

    int startA = offsets[iA], endA = offsets[iA + 1];
    int startB = 0, endB = 0;
    if (iB < N) { startB = endA; endB = offsets[iB + 1]; }

    float4 att4 = *(const float4*)(att + hq * 4);
    const float L2E = 1.4426950408889634f;
    att4.x *= L2E; att4.y *= L2E; att4.z *= L2E; att4.w *= L2E;

    const _Float16 ns = (_Float16)0.2f;
    half4 hzero = {(_Float16)0.f, (_Float16)0.f, (_Float16)0.f, (_Float16)0.f};

    half4 xrA = *(const half4*)(xr + (long)iA * 32 + hq * 4);
    half4 xrB = hzero;
    if (iB < N) xrB = *(const half4*)(xr + (long)iB * 32 + hq * 4);

    float denomA = 0.f, denomB = 0.f;
    float4 accA = {0.f, 0.f, 0.f, 0.f};
    float4 accB = {0.f, 0.f, 0.f, 0.f};

    int itA = (endA - startA + 7) >> 3;
    int itB = (endB - startB + 7) >> 3;
    int iters = max(itA, itB);

    int pA = startA + e8, pB = startB + e8;
    int sA = -1, sB = -1;
    if (pA < endA) sA = *(const int*)(csrb + ((unsigned)pA << 2));
    if (pB < endB) sB = *(const int*)(csrb + ((unsigned)pB << 2));

    for (int it = 0; it < iters; ++it) {
        half4 xa = hzero;
        half4 xb = hzero;
        if (sA >= 0) xa = *(const half4*)(xlb + (((unsigned)sA << 6) | hq8));
        if (sB >= 0) xb = *(const half4*)(xlb + (((unsigned)sB << 6) | hq8));
        // prefetch next iteration's csr indices (independent of compute)
        pA += 8; pB += 8;
        int sA2 = -1, sB2 = -1;
        if (pA < endA) sA2 = *(const int*)(csrb + ((unsigned)pA << 2));
        if (pB < endB) sB2 = *(const int*)(csrb + ((unsigned)pB << 2));

        // ---- stream A ----
        {
            half4 s = xa + xrA;                          // 2x v_pk_add_f16
            half4 m = s * ns;                            // 2x v_pk_mul_f16
            half4 tt = __builtin_elementwise_max(s, m);  // 2x v_pk_max_f16
            float l = fmaf((float)tt[0], att4.x,
                      fmaf((float)tt[1], att4.y,
                      fmaf((float)tt[2], att4.z,
                           (float)tt[3] * att4.w)));     // v_fma_mix chain
            l += __shfl_xor(l, 1);
            l += __shfl_xor(l, 2);
            l += __shfl_xor(l, 4);
            float wA = __builtin_amdgcn_exp2f(l);        // l is log2-scaled
            wA = (sA >= 0) ? wA : 0.f;
            denomA += wA;
            accA.x = fmaf(wA, (float)xa[0], accA.x);     // v_fma_mix
            accA.y = fmaf(wA, (float)xa[1], accA.y);
            accA.z = fmaf(wA, (float)xa[2], accA.z);
            accA.w = fmaf(wA, (float)xa[3], accA.w);
        }
        // ---- stream B ----
        {
            half4 s = xb + xrB;
            half4 m = s * ns;
            half4 tt = __builtin_elementwise_max(s, m);
            float l = fmaf((float)tt[0], att4.x,
                      fmaf((float)tt[1], att4.y,
                      fmaf((float)tt[2], att4.z,
                           (float)tt[3] * att4.w)));
            l += __shfl_xor(l, 1);
            l += __shfl_xor(l, 2);
            l += __shfl_xor(l, 4);
            float wB = __builtin_amdgcn_exp2f(l);
            wB = (sB >= 0) ? wB : 0.f;
            denomB += wB;
            accB.x = fmaf(wB, (float)xb[0], accB.x);
            accB.y = fmaf(wB, (float)xb[1], accB.y);
            accB.z = fmaf(wB, (float)xb[2], accB.z);
            accB.w = fmaf(wB, (float)xb[3], accB.w);
        }
        sA = sA2; sB = sB2;
    }

    // reduce across the 8 edge groups (xor 8,16,32) -> ALL lanes hold sums
    denomA += __shfl_xor(denomA, 8); denomA += __shfl_xor(denomA, 16); denomA += __shfl_xor(denomA, 32);
    denomB += __shfl_xor(denomB, 8); denomB += __shfl_xor(denomB, 16); denomB += __shfl_xor(denomB, 32);
    accA.x += __shfl_xor(accA.x, 8); accA.x += __shfl_xor(accA.x, 16); accA.x += __shfl_xor(accA.x, 32);
    accA.y += __shfl_xor(accA.y, 8); accA.y += __shfl_xor(accA.y, 16); accA.y += __shfl_xor(accA.y, 32);
    accA.z += __shfl_xor(accA.z, 8); accA.z += __shfl_xor(accA.z, 16); accA.z += __shfl_xor(accA.z, 32);
    accA.w += __shfl_xor(accA.w, 8); accA.w += __shfl_xor(accA.w, 16); accA.w += __shfl_xor(accA.w, 32);
    accB.x += __shfl_xor(accB.x, 8); accB.x += __shfl_xor(accB.x, 16); accB.x += __shfl_xor(accB.x, 32);
    accB.y += __shfl_xor(accB.y, 8); accB.y += __shfl_xor(accB.y, 16); accB.y += __shfl_xor(accB.y, 32);
    accB.z += __shfl_xor(accB.z, 8); accB.z += __shfl_xor(accB.z, 16); accB.z += __shfl_xor(accB.z, 32);
    accB.w += __shfl_xor(accB.w, 8); accB.w += __shfl_xor(accB.w, 16); accB.w += __shfl_xor(accB.w, 32);

    const float4 b4 = *(const float4*)(bias + hq * 4);

    if (MODE == 0) {
        // build outputs (all lanes -- cheap, SIMD)
        float invA = 1.0f / denomA;
        float4 oA;
        oA.x = fmaxf(fmaf(accA.x, invA, b4.x), 0.f);
        oA.y = fmaxf(fmaf(accA.y, invA, b4.y), 0.f);
        oA.z = fmaxf(fmaf(accA.z, invA, b4.z), 0.f);
        oA.w = fmaxf(fmaf(accA.w, invA, b4.w), 0.f);
        float4 oB = {0.f, 0.f, 0.f, 0.f};
        if (iB < N) {
            float invB = 1.0f / denomB;
            oB.x = fmaxf(fmaf(accB.x, invB, b4.x), 0.f);
            oB.y = fmaxf(fmaf(accB.y, invB, b4.y), 0.f);
            oB.z = fmaxf(fmaf(accB.z, invB, b4.z), 0.f);
            oB.w = fmaxf(fmaf(accB.w, invB, b4.w), 0.f);
        }
        // stage the two h-rows in wave-local LDS (broadcast source)
        if (lane < 8) {
            *(float4*)&sO[wv][0][hq * 4] = oA;
        } else if (lane < 16) {
            *(float4*)&sO[wv][1][hq * 4] = oB;   // garbage ok if iB>=N (unused)
        }
        __builtin_amdgcn_wave_barrier();         // pin write->read order
        // layer-2 matvec: lane l -> output col (l&31) of node (l>>5).
        // Weights quad-k packed: float4 at (kb*32 + hcol)*4 floats.
        int hcol = lane & 31;
        int nrow = lane >> 5;
        const float* row = &sO[wv][nrow][0];
        const float* wlq = w2t + hcol * 4;           // + kb*128 per step
        const float* wrq = w2t + 1024 + hcol * 4;
        float al = 0.f, ar = 0.f;
#pragma unroll
        for (int kb = 0; kb < 8; kb++) {
            float4 r4 = *(const float4*)(row + kb * 4);      // ds_read bcast
            float4 wl4 = *(const float4*)(wlq + kb * 128);   // dwordx4 coal.
            float4 wr4 = *(const float4*)(wrq + kb * 128);
            al = fmaf(r4.x, wl4.x, al);
            al = fmaf(r4.y, wl4.y, al);
            al = fmaf(r4.z, wl4.z, al);
            al = fmaf(r4.w, wl4.w, al);
            ar = fmaf(r4.x, wr4.x, ar);
            ar = fmaf(r4.y, wr4.y, ar);
            ar = fmaf(r4.z, wr4.z, ar);
            ar = fmaf(r4.w, wr4.w, ar);
        }
        long nn = nrow ? (long)iB : (long)iA;
        if (!nrow || iB < N) {
            oxl[nn * 32 + hcol] = (_Float16)al;
            oxr[nn * 32 + hcol] = (_Float16)ar;
        }
    } else {
        // proven coalesced fp32 row write (R0-R4 epilogue)
        if (lane < 8) {
            float inv = 1.0f / denomA;
            float4 o;
            o.x = fmaxf(fmaf(accA.x, inv, b4.x), 0.f);
            o.y = fmaxf(fmaf(accA.y, inv, b4.y), 0.f);
            o.z = fmaxf(fmaf(accA.z, inv, b4.z), 0.f);
            o.w = fmaxf(fmaf(accA.w, inv, b4.w), 0.f);
            *(float4*)(out + (long)iA * 32 + hq * 4) = o;
        } else if (lane < 16 && iB < N) {
            float inv = 1.0f / denomB;
            float4 o;
            o.x = fmaxf(fmaf(accB.x, inv, b4.x), 0.f);
            o.y = fmaxf(fmaf(accB.y, inv, b4.y), 0.f);
            o.z = fmaxf(fmaf(accB.z, inv, b4.z), 0.f);
            o.w = fmaxf(fmaf(accB.w, inv, b4.w), 0.f);
            *(float4*)(out + (long)iB * 32 + hq * 4) = o;
        }
    }
}

// ---------------------------------------------------------------------------
// Fused mean-pool + linear head (R0-R4 proven): one block per graph,
// sequential coalesced h2v reads, zero atomics.
// ---------------------------------------------------------------------------
__global__ __launch_bounds__(WG) void k_pool(const float* __restrict__ h2v,
                                             const int* __restrict__ gstart,
                                             const float* __restrict__ Wlin,
                                             const float* __restrict__ blin,
                                             float* __restrict__ out, int G) {
    __shared__ float red[WG];
    int g = blockIdx.x;
    int t = threadIdx.x;
    int h = t & 31;
    int grp = t >> 5;                       // 8 groups of 32 lanes
    int s = gstart[g], e = gstart[g + 1];
    float acc = 0.f;
    for (int n = s + grp; n < e; n += 8)
        acc += h2v[(long)n * 32 + h];
    red[t] = acc;
    __syncthreads();
    if (grp == 0) {
        float a = red[h] + red[h + 32] + red[h + 64] + red[h + 96]
                + red[h + 128] + red[h + 160] + red[h + 192] + red[h + 224];
        int cnt = e - s;
        float c = (float)(cnt > 1 ? cnt : 1);
        float f = a / c;
        out[G * 4 + g * 32 + h] = f;        // features block
        float p0 = f * Wlin[h * 4 + 0];
        float p1 = f * Wlin[h * 4 + 1];
        float p2 = f * Wlin[h * 4 + 2];
        float p3 = f * Wlin[h * 4 + 3];
        for (int off = 1; off < 32; off <<= 1) {
            p0 += __shfl_xor(p0, off);
            p1 += __shfl_xor(p1, off);
            p2 += __shfl_xor(p2, off);
            p3 += __shfl_xor(p3, off);
        }
        if (h == 0) {
            out[g * 4 + 0] = p0 + blin[0];
            out[g * 4 + 1] = p1 + blin[1];
            out[g * 4 + 2] = p2 + blin[2];
            out[g * 4 + 3] = p3 + blin[3];
        }
    }
}

// ---------------------------------------------------------------------------
extern "C" void kernel_launch(void* const* d_in, const int* in_sizes, int n_in,
                              void* d_out, int out_size, void* d_ws, size_t ws_size,
                              hipStream_t stream) {
    const float* x    = (const float*)d_in[0];
    const int*   ei   = (const int*)d_in[1];
    const int*   batch= (const int*)d_in[2];
    const float* Wl1  = (const float*)d_in[3];
    const float* Wr1  = (const float*)d_in[4];
    const float* att1 = (const float*)d_in[5];
    const float* b1   = (const float*)d_in[6];
    const float* Wl2  = (const float*)d_in[7];
    const float* Wr2  = (const float*)d_in[8];
    const float* att2 = (const float*)d_in[9];
    const float* b2   = (const float*)d_in[10];
    const float* Wlin = (const float*)d_in[11];
    const float* blin = (const float*)d_in[12];
    float* out = (float*)d_out;

    const int N   = in_sizes[2];
    const int Cin = in_sizes[0] / N;
    const int E   = in_sizes[1] / 2;
    const int G   = out_size / 36;
    const int* src = ei;
    const int* dst = ei + E;
    const int NB  = (N + NPB - 1) >> NPB_SHIFT;   // buckets (<=512)

    // workspace carve (256B aligned)
    char* w = (char*)d_ws;
    auto alloc = [&](size_t bytes) {
        char* p = w;
        w += (bytes + 255) & ~(size_t)255;
        return p;
    };
    int* offsets = (int*)alloc((size_t)(N + 1) * 4);
    int* gstart  = (int*)alloc((size_t)(G + 1) * 4);
    int* gcnt    = (int*)alloc((size_t)NB * 4);
    int* csr_src = (int*)alloc((size_t)(E + N) * 4);
    unsigned* staging = (unsigned*)alloc((size_t)NB * CAP * 4);
    float* w2t   = (float*)alloc((size_t)2048 * 4);
    _Float16* xl  = (_Float16*)alloc((size_t)N * 32 * 2);
    _Float16* xr  = (_Float16*)alloc((size_t)N * 32 * 2);
    _Float16* xl2 = (_Float16*)alloc((size_t)N * 32 * 2);
    _Float16* xr2 = (_Float16*)alloc((size_t)N * 32 * 2);
    float* h2v    = (float*)alloc((size_t)N * 32 * 4);

    hipMemsetAsync(gcnt, 0, (size_t)NB * 4, stream);

    int binBlocks = (E + BIN_CHUNK - 1) / BIN_CHUNK;
    int linBlocks = (N + LIN_NPB - 1) / LIN_NPB;
    int stBlocks  = (G + 1 + 511) / 512;

    // front: CSR bin + layer-1 lin + gstart + W2 repack, one kernel
    k_front<<<binBlocks + linBlocks + stBlocks + 1, 512, 0, stream>>>(
        src, dst, gcnt, staging, E, NB, binBlocks,
        x, Wl1, Wr1, xl, xr, N, Cin, linBlocks,
        batch, gstart, G, stBlocks, Wl2, Wr2, w2t);

    // CSR place (512 threads, LDS-staged slab, wave-scan)
    k_bucket<<<NB, 512, 0, stream>>>(staging, gcnt, offsets, csr_src, N, NB);

    int waves = (N + 1) / 2;
    int gat_grid = (waves + 3) / 4;               // 4 waves per 256-block

    // layer 1 aggregate + fused layer-2 transform (writes xl2/xr2 directly)
    k_gat<0><<<gat_grid, WG, 0, stream>>>(xl, xr, offsets, csr_src, att1, b1,
                                          N, w2t, xl2, xr2, nullptr);

    // layer 2 aggregate, fp32 rows to h2v
    k_gat<1><<<gat_grid, WG, 0, stream>>>(xl2, xr2, offsets, csr_src, att2, b2,
                                          N, nullptr, nullptr, nullptr, h2v);

    // pool + head
    k_pool<<<G, WG, 0, stream>>>(h2v, gstart, Wlin, blin, out, G);
}